// Round 4
// baseline (140.836 us; speedup 1.0000x reference)
//
#include <hip/hip_runtime.h>

// SpatialBorderLoss — LDS-staged, row-per-thread.
//
// R3 post-mortem: per-point + unroll stuck at ~40us (floor 17us). Cause: 65
// VALU/point (quad + edge constants + cx/cy recomputed 9x/row, p/9 magic div)
// and 8B/lane pts loads. Fix: block stages 256-row pts tile (18KB) via
// coalesced float4 into LDS; thread t = row t; quad loaded once/row (direct
// global, 32B stride); per-row hoist of d_e, ex_e, sign flags, cx, cy; parity
// via XOR; 0.2 scale folded into finalize. ~45 VALU/point, demand-only L1
// traffic. 1 block per tile, 1 barrier, 8 blocks/CU (18.4KB LDS).
//
// ws: double part_sum[nb] ; uint part_cnt[nb] ; uint part_wpos[nb]

#define SBL_BLOCK 256
#define SBL_TILE  256   // rows per block

__global__ void __launch_bounds__(SBL_BLOCK) sbl_main(
    const float* __restrict__ pts,      // [n,18]
    const float* __restrict__ quads,    // [n,8]
    const float* __restrict__ weight,   // [n]
    double* __restrict__ part_sum,
    unsigned int* __restrict__ part_cnt,
    unsigned int* __restrict__ part_wpos,
    int n)
{
    __shared__ float s_pts[SBL_TILE * 18];          // 18432 B, raw row-major

    const int tid  = threadIdx.x;
    const int base = blockIdx.x * SBL_TILE;
    const int rows = min(SBL_TILE, n - base);
    const bool have_row = (tid < rows);

    float local_sum = 0.0f;
    unsigned int local_cnt = 0u, local_wpos = 0u;

    // ---- issue my quad + weight loads early (latency overlaps staging) ----
    float4 qa = make_float4(0.f, 0.f, 0.f, 0.f);
    float4 qb = make_float4(0.f, 0.f, 0.f, 0.f);
    if (have_row) {
        const float4* q4 = reinterpret_cast<const float4*>(quads) + (size_t)(base + tid) * 2;
        qa = q4[0];
        qb = q4[1];
    }
    {
        const int gi = base + tid;
        if (gi < n) local_wpos = (weight[gi] > 0.0f) ? 1u : 0u;
    }

    // ---- stage pts tile: coalesced float4 streaming ----
    if (rows == SBL_TILE) {
        const float4* g4 = reinterpret_cast<const float4*>(pts + (size_t)base * 18);
        float4* s4 = reinterpret_cast<float4*>(s_pts);
        #pragma unroll
        for (int k = 0; k < 5; ++k) {                 // 1152 float4s, last iter half-active
            const int idx = k * SBL_BLOCK + tid;
            if (idx < (SBL_TILE * 18) / 4) s4[idx] = g4[idx];
        }
    } else {                                          // tail tile (once per grid)
        const float2* g2 = reinterpret_cast<const float2*>(pts + (size_t)base * 18);
        float2* s2 = reinterpret_cast<float2*>(s_pts);
        const int nf2 = rows * 9;
        for (int idx = tid; idx < nf2; idx += SBL_BLOCK) s2[idx] = g2[idx];
    }
    __syncthreads();

    // ---- compute: thread t = row t, 9 points from LDS ----
    if (have_row) {
        const float vx0 = qa.x, vy0 = qa.y, vx1 = qa.z, vy1 = qa.w;
        const float vx2 = qb.x, vy2 = qb.y, vx3 = qb.z, vy3 = qb.w;
        const float cx = (vx0 + vx2) * 0.5f;
        const float cy = (vy0 + vy2) * 0.5f;
        // edge e pairs (v_e, v_{e-1 mod 4}) per jnp.roll(v,1)
        const float d0 = vy3 - vy0, d1 = vy0 - vy1, d2 = vy1 - vy2, d3 = vy2 - vy3;
        const float e0 = vx3 - vx0, e1 = vx0 - vx1, e2 = vx1 - vx2, e3 = vx2 - vx3;
        const bool  n0 = d0 < 0.0f, n1 = d1 < 0.0f, n2 = d2 < 0.0f, n3 = d3 < 0.0f;

        const float2* prow = reinterpret_cast<const float2*>(s_pts + tid * 18);
        #pragma unroll
        for (int k = 0; k < 9; ++k) {
            const float2 p = prow[k];
            const float px = p.x, py = p.y;

            const bool c0 = vy0 > py, c1 = vy1 > py, c2 = vy2 > py, c3 = vy3 > py;
            const bool s0 = c0 != c3, s1 = c1 != c0, s2 = c2 != c1, s3 = c3 != c2;

            // straddle pins sign of d; divide -> sign-adjusted mul-compare
            const float t0 = py - vy0, t1 = py - vy1, t2 = py - vy2, t3 = py - vy3;
            const float m0 = e0 * t0, m1 = e1 * t1, m2 = e2 * t2, m3 = e3 * t3;
            const float l0 = (px - vx0) * d0, l1 = (px - vx1) * d1;
            const float l2 = (px - vx2) * d2, l3 = (px - vx3) * d3;

            const bool x0 = s0 && ((l0 < m0) != n0);
            const bool x1 = s1 && ((l1 < m1) != n1);
            const bool x2 = s2 && ((l2 < m2) != n2);
            const bool x3 = s3 && ((l3 < m3) != n3);

            const bool inside = (x0 != x1) != (x2 != x3);   // parity of crossings
            if (!inside) {
                const float dx = px - cx;
                const float dy = py - cy;
                local_sum += sqrtf(fmaf(dx, dx, dy * dy));  // 0.2 applied in finalize
                local_cnt += 1u;
            }
        }
    }

    // ---- wave (64) reduction ----
    #pragma unroll
    for (int off = 32; off > 0; off >>= 1) {
        local_sum  += __shfl_down(local_sum, off, 64);
        local_cnt  += __shfl_down(local_cnt, off, 64);
        local_wpos += __shfl_down(local_wpos, off, 64);
    }

    // ---- block reduction across 4 waves ----
    __shared__ float        r_sum[4];
    __shared__ unsigned int r_cnt[4];
    __shared__ unsigned int r_wpos[4];
    const int lane = tid & 63;
    const int wave = tid >> 6;
    if (lane == 0) { r_sum[wave] = local_sum; r_cnt[wave] = local_cnt; r_wpos[wave] = local_wpos; }
    __syncthreads();
    if (tid == 0) {
        double bsum = 0.0;
        unsigned int bcnt = 0u, bwpos = 0u;
        #pragma unroll
        for (int i = 0; i < 4; ++i) { bsum += (double)r_sum[i]; bcnt += r_cnt[i]; bwpos += r_wpos[i]; }
        part_sum[blockIdx.x]  = bsum;      // own slot: no init, no atomics
        part_cnt[blockIdx.x]  = bcnt;
        part_wpos[blockIdx.x] = bwpos;
    }
}

__global__ void __launch_bounds__(256) sbl_finalize(
    const double* __restrict__ part_sum,
    const unsigned int* __restrict__ part_cnt,
    const unsigned int* __restrict__ part_wpos,
    float* __restrict__ out,
    int nblocks)
{
    const int tid = threadIdx.x;
    double s = 0.0;
    unsigned int c = 0u, w = 0u;
    for (int i = tid; i < nblocks; i += 256) {
        s += part_sum[i];
        c += part_cnt[i];
        w += part_wpos[i];
    }
    #pragma unroll
    for (int off = 32; off > 0; off >>= 1) {
        s += __shfl_down(s, off, 64);
        c += __shfl_down(c, off, 64);
        w += __shfl_down(w, off, 64);
    }
    __shared__ double       fs[4];
    __shared__ unsigned int fc[4], fw[4];
    const int lane = tid & 63, wave = tid >> 6;
    if (lane == 0) { fs[wave] = s; fc[wave] = c; fw[wave] = w; }
    __syncthreads();
    if (tid == 0) {
        double ts = 0.0; unsigned int tc = 0u, tw = 0u;
        #pragma unroll
        for (int k = 0; k < 4; ++k) { ts += fs[k]; tc += fc[k]; tw += fw[k]; }
        const double loss_sb = (tc > 0u) ? (0.2 * ts / (double)tc) : 0.0;
        const double avg_factor = (double)tw + 1e-6;
        out[0] = (float)(loss_sb / avg_factor);
    }
}

extern "C" void kernel_launch(void* const* d_in, const int* in_sizes, int n_in,
                              void* d_out, int out_size, void* d_ws, size_t ws_size,
                              hipStream_t stream) {
    const float* pts    = (const float*)d_in[0];   // [n,18]
    const float* quads  = (const float*)d_in[1];   // [n,8]
    const float* weight = (const float*)d_in[2];   // [n]
    float* out = (float*)d_out;

    const int n = in_sizes[2];
    const int nblocks = (n + SBL_TILE - 1) / SBL_TILE;

    double*       part_sum  = (double*)d_ws;
    unsigned int* part_cnt  = (unsigned int*)((char*)d_ws + (size_t)nblocks * sizeof(double));
    unsigned int* part_wpos = (unsigned int*)((char*)d_ws + (size_t)nblocks * (sizeof(double) + sizeof(unsigned int)));

    sbl_main<<<nblocks, SBL_BLOCK, 0, stream>>>(pts, quads, weight,
                                                part_sum, part_cnt, part_wpos, n);
    sbl_finalize<<<1, 256, 0, stream>>>(part_sum, part_cnt, part_wpos, out, nblocks);
}